// Round 2
// baseline (283.944 us; speedup 1.0000x reference)
//
#include <hip/hip_runtime.h>
#include <math.h>

// SchNet interaction, MFMA bf16-split, swizzled-weight design, R2.
// Nb=8, Na=1024, Nnbh=64, A=F=128, S=50.
// prep u32 layout (fragment-linear swizzled order, 1 KB/wave coalesced):
//   W1S    @0      (4096):  [ftile][kh][l][4]   W_f1 bf16, K 50->64 pad
//   W2S    @4096   (8192):  [ftile][kq][l][4]   W_f2 bf16
//   F2O_h  @12288, F2O_l @20480   W_f2out hi/lo split, swizzled
//   DEN_h  @28672, DEN_l @36864   W_dense  hi/lo split
//   IN2F_h @45056, IN2F_l @53248  W_in2f   hi/lo split
// fragment addr for (ftile,kq): (ftile*4+kq)*256 + l*4 (u32), f = 16*ftile+m.
//
// R2 change: K2 gather (cn * y[nb][f]) prefetched into registers BEFORE
// phase A so the ~500-cycle nbrs->y load chain hides under phase-A compute;
// phase-B mt loop fully unrolled (static indexing), accumulators ILP-split.

#define RCUT  5.0f
#define LOG2F_ 0.69314718055994530942f
#define LOG2E_ 1.44269504088896340736f

typedef __bf16 bf16x8_t __attribute__((ext_vector_type(8)));
typedef float  f32x4_t  __attribute__((ext_vector_type(4)));

static __device__ __forceinline__ float sspf(float x) {
    // softplus(x) - ln2 = max(x,0) + ln2*log2(1 + 2^(-|x|*log2e)) - ln2
    float e  = exp2f(-LOG2E_ * fabsf(x));
    float lg = log2f(1.0f + e);
    return fmaf(lg, LOG2F_, fmaxf(x, 0.0f) - LOG2F_);
}
static __device__ __forceinline__ unsigned pack2h(__bf16 a, __bf16 b) {
    union { __bf16 h[2]; unsigned u; } un; un.h[0] = a; un.h[1] = b; return un.u;
}
static __device__ __forceinline__ unsigned pack2f(float a, float b) {
    return pack2h((__bf16)a, (__bf16)b);
}

// ---------------------------------------------------------------------------
// K0: weight prep (all swizzled conversions). 240 blocks x 256 = 61440 items.
// ---------------------------------------------------------------------------
__global__ __launch_bounds__(256) void prep_kernel(
    const float* __restrict__ W1, const float* __restrict__ W2,
    const float* __restrict__ Wb,   // W_f2out
    const float* __restrict__ Wc,   // W_dense
    const float* __restrict__ Wf,   // W_in2f
    unsigned* __restrict__ prep)
{
    int i = blockIdx.x * 256 + threadIdx.x;
    if (i < 4096) {                        // W1S (K pad 50->64)
        int sw = i >> 10, ft = (i >> 9) & 1, kh = (i >> 8) & 1;
        int sl = (i >> 2) & 63, j = i & 3;
        int sq = sl >> 4, sm = sl & 15;
        int f = 32 * sw + 16 * ft + sm;
        int c = kh * 16 + 4 * sq + j;
        int k0 = 2 * c, k1 = 2 * c + 1;
        float a = (k0 < 50) ? W1[f * 50 + k0] : 0.0f;
        float b = (k1 < 50) ? W1[f * 50 + k1] : 0.0f;
        prep[i] = pack2f(a, b);
    } else if (i < 12288) {                // W2S
        int s = i - 4096;
        int sw = s >> 11, ft = (s >> 10) & 1, kq = (s >> 8) & 3;
        int sl = (s >> 2) & 63, j = s & 3;
        int sq = sl >> 4, sm = sl & 15;
        int f = 32 * sw + 16 * ft + sm;
        int c = 16 * kq + 4 * sq + j;
        float2 wv = ((const float2*)W2)[f * 64 + c];
        prep[i] = pack2f(wv.x, wv.y);
    } else {                               // f2out / dense / in2f, hi+lo
        int s = i - 12288;
        int L = s >> 14;                   // 0: f2out, 1: dense, 2: in2f
        int r = s & 16383;
        int hl = r >> 13;                  // 0: hi, 1: lo
        int e = r & 8191;
        int sw = e >> 11, ft = (e >> 10) & 1, kq = (e >> 8) & 3;
        int sl = (e >> 2) & 63, j = e & 3;
        int sq = sl >> 4, sm = sl & 15;
        int f = 32 * sw + 16 * ft + sm;
        int c = 16 * kq + 4 * sq + j;
        const float* src = (L == 0) ? Wb : (L == 1) ? Wc : Wf;
        float2 wv = ((const float2*)src)[f * 64 + c];
        if (hl == 0) {
            prep[i] = pack2h((__bf16)wv.x, (__bf16)wv.y);
        } else {
            __bf16 h0 = (__bf16)wv.x, h1 = (__bf16)wv.y;
            prep[i] = pack2f(wv.x - (float)h0, wv.y - (float)h1);
        }
    }
}

// ---------------------------------------------------------------------------
// K1: y = x @ W_in2f^T using preconverted swizzled weights.
// 1024 blocks: (atom-tile of 16) x (f-half of 64). 4 blocks/CU.
// ---------------------------------------------------------------------------
__global__ __launch_bounds__(256, 4) void k1_kernel(
    const float* __restrict__ x,
    const unsigned* __restrict__ Wh, const unsigned* __restrict__ Wl,
    float* __restrict__ yout)
{
    __shared__ __bf16 Ah[16 * 136];
    __shared__ __bf16 Al[16 * 136];

    const int t = threadIdx.x;
    const int atom0 = (blockIdx.x >> 1) * 16;
    const int fh = blockIdx.x & 1;
    const int w = t >> 6, l = t & 63, m = l & 15, q = l >> 4;

    {
        const float4* A4 = (const float4*)(x + (size_t)atom0 * 128);
        unsigned* AhU = (unsigned*)Ah;
        unsigned* AlU = (unsigned*)Al;
        #pragma unroll
        for (int r = 0; r < 2; ++r) {
            int lin4 = r * 256 + t;
            int a = lin4 >> 5, k4 = lin4 & 31;
            float4 xv = A4[lin4];
            __bf16 h0=(__bf16)xv.x, h1=(__bf16)xv.y, h2=(__bf16)xv.z, h3=(__bf16)xv.w;
            int idx = a * 68 + 2 * k4;
            AhU[idx]     = pack2h(h0, h1);
            AhU[idx + 1] = pack2h(h2, h3);
            AlU[idx]     = pack2f(xv.x - (float)h0, xv.y - (float)h1);
            AlU[idx + 1] = pack2f(xv.z - (float)h2, xv.w - (float)h3);
        }
    }
    __syncthreads();

    const int ftile = fh * 4 + w;
    const int f = 16 * ftile + m;
    f32x4_t acc = {0.f, 0.f, 0.f, 0.f};
    #pragma unroll
    for (int kk = 0; kk < 4; ++kk) {
        int off = m * 136 + 32 * kk + 8 * q;
        bf16x8_t ah = *(const bf16x8_t*)&Ah[off];
        bf16x8_t al = *(const bf16x8_t*)&Al[off];
        int wo = (ftile * 4 + kk) * 256 + l * 4;
        bf16x8_t wh = *(const bf16x8_t*)(Wh + wo);
        bf16x8_t wl = *(const bf16x8_t*)(Wl + wo);
        acc = __builtin_amdgcn_mfma_f32_16x16x32_bf16(ah, wh, acc, 0, 0, 0);
        acc = __builtin_amdgcn_mfma_f32_16x16x32_bf16(ah, wl, acc, 0, 0, 0);
        acc = __builtin_amdgcn_mfma_f32_16x16x32_bf16(al, wh, acc, 0, 0, 0);
    }
    #pragma unroll
    for (int r = 0; r < 4; ++r)
        yout[(size_t)(atom0 + 4 * q + r) * 128 + f] = acc[r];
}

// ---------------------------------------------------------------------------
// K2 interaction. 1 atom/block, 256 thr = 4 waves, ONE barrier.
// Gather values prefetched to registers before phase A (latency hidden).
// ---------------------------------------------------------------------------
__global__ __launch_bounds__(256, 4) void interaction_kernel(
    const float* __restrict__ rij, const int* __restrict__ nbrs,
    const float* __restrict__ mask, const float* __restrict__ fij,
    const float* __restrict__ b1, const float* __restrict__ b2,
    const unsigned* __restrict__ W1S,   // swizzled [8][2][64][4] u32
    const unsigned* __restrict__ W2S,   // swizzled [8][4][64][4] u32
    const float* __restrict__ y, float* __restrict__ v)
{
    __shared__ __bf16 Hh[64 * 136];
    __shared__ __bf16 Hl[64 * 136];

    const int t  = threadIdx.x;
    const int a  = blockIdx.x;
    const int bi = a >> 10;
    const int p0 = a * 64;
    const int w = t >> 6, l = t & 63, m = l & 15, q = l >> 4;
    const int f0 = 32 * w + m;
    const int f1 = f0 + 16;

    // ---- gather prefetch: cy = cn * y[nb][f], issued before phase A ----
    // rij/mask/nbrs loads are 16-lane broadcast; y loads are 64B-coalesced
    // per 16-lane group. Latency hides under phase-A MFMA/VALU work.
    float cy0[16], cy1[16];
    #pragma unroll
    for (int i = 0; i < 16; ++i) {
        int mt = i >> 2, r = i & 3;
        int n = 16 * mt + 4 * q + r;
        float rr = rij[p0 + n];
        float cn = (rr <= RCUT) ? mask[p0 + n] : 0.0f;
        int nbv = (bi << 10) + nbrs[p0 + n];
        const float* yrow = y + (size_t)nbv * 128;
        cy0[i] = cn * yrow[f0];
        cy1[i] = cn * yrow[f1];
    }

    // ---- phase A: H[n][f] = ssp(fij @ W1^T + b1), wave owns 16 rows ----
    {
        const float* frow = fij + (size_t)(p0 + 16 * w + m) * 50;
        float kv[16];
        #pragma unroll
        for (int j2 = 0; j2 < 4; ++j2) {
            float2 xv = *(const float2*)(frow + 8 * q + 2 * j2);
            kv[2 * j2] = xv.x; kv[2 * j2 + 1] = xv.y;
        }
        #pragma unroll
        for (int j2 = 0; j2 < 4; ++j2) {
            int k = 32 + 8 * q + 2 * j2;
            float2 xv = make_float2(0.f, 0.f);
            if (k < 50) xv = *(const float2*)(frow + k);
            kv[8 + 2 * j2] = xv.x; kv[9 + 2 * j2] = xv.y;
        }
        union { __bf16 h[16]; bf16x8_t v8[2]; } uh, ul;
        #pragma unroll
        for (int k = 0; k < 16; ++k) {
            __bf16 hi = (__bf16)kv[k];
            uh.h[k] = hi;
            ul.h[k] = (__bf16)(kv[k] - (float)hi);
        }
        #pragma unroll 2
        for (int ftile = 0; ftile < 8; ++ftile) {
            float bb = b1[16 * ftile + m];
            f32x4_t acch = {bb, bb, bb, bb};
            f32x4_t accl = {0.f, 0.f, 0.f, 0.f};
            bf16x8_t w0 = *(const bf16x8_t*)(W1S + (ftile * 2 + 0) * 256 + l * 4);
            bf16x8_t w1 = *(const bf16x8_t*)(W1S + (ftile * 2 + 1) * 256 + l * 4);
            acch = __builtin_amdgcn_mfma_f32_16x16x32_bf16(uh.v8[0], w0, acch, 0, 0, 0);
            accl = __builtin_amdgcn_mfma_f32_16x16x32_bf16(ul.v8[0], w0, accl, 0, 0, 0);
            acch = __builtin_amdgcn_mfma_f32_16x16x32_bf16(uh.v8[1], w1, acch, 0, 0, 0);
            accl = __builtin_amdgcn_mfma_f32_16x16x32_bf16(ul.v8[1], w1, accl, 0, 0, 0);
            #pragma unroll
            for (int r = 0; r < 4; ++r) {
                int n = 16 * w + 4 * q + r;
                float hv = sspf(acch[r] + accl[r]);
                __bf16 hh = (__bf16)hv;
                Hh[n * 136 + 16 * ftile + m] = hh;
                Hl[n * 136 + 16 * ftile + m] = (__bf16)(hv - (float)hh);
            }
        }
    }
    __syncthreads();   // the ONLY barrier

    // ---- phase B: Wm = H @ W2^T + b2, fused aggregate on registers ----
    const float bb2_0 = b2[f0], bb2_1 = b2[f1];
    bf16x8_t w2f0[4], w2f1[4];
    #pragma unroll
    for (int kq = 0; kq < 4; ++kq) {
        w2f0[kq] = *(const bf16x8_t*)(W2S + ((w * 2 + 0) * 4 + kq) * 256 + l * 4);
        w2f1[kq] = *(const bf16x8_t*)(W2S + ((w * 2 + 1) * 4 + kq) * 256 + l * 4);
    }
    float pv0 = 0.0f, pv1 = 0.0f;
    #pragma unroll
    for (int mt = 0; mt < 4; ++mt) {
        f32x4_t a0h = {bb2_0, bb2_0, bb2_0, bb2_0};
        f32x4_t a0l = {0.f, 0.f, 0.f, 0.f};
        f32x4_t a1h = {bb2_1, bb2_1, bb2_1, bb2_1};
        f32x4_t a1l = {0.f, 0.f, 0.f, 0.f};
        #pragma unroll
        for (int kq = 0; kq < 4; ++kq) {
            int hoff = (16 * mt + m) * 136 + 32 * kq + 8 * q;
            bf16x8_t hh = *(const bf16x8_t*)&Hh[hoff];
            bf16x8_t hl = *(const bf16x8_t*)&Hl[hoff];
            a0h = __builtin_amdgcn_mfma_f32_16x16x32_bf16(hh, w2f0[kq], a0h, 0, 0, 0);
            a0l = __builtin_amdgcn_mfma_f32_16x16x32_bf16(hl, w2f0[kq], a0l, 0, 0, 0);
            a1h = __builtin_amdgcn_mfma_f32_16x16x32_bf16(hh, w2f1[kq], a1h, 0, 0, 0);
            a1l = __builtin_amdgcn_mfma_f32_16x16x32_bf16(hl, w2f1[kq], a1l, 0, 0, 0);
        }
        #pragma unroll
        for (int r = 0; r < 4; ++r) {
            float s0 = a0h[r] + a0l[r];
            float s1 = a1h[r] + a1l[r];
            pv0 = fmaf(cy0[mt * 4 + r], s0, pv0);
            pv1 = fmaf(cy1[mt * 4 + r], s1, pv1);
        }
    }
    pv0 += __shfl_xor(pv0, 16);
    pv0 += __shfl_xor(pv0, 32);
    pv1 += __shfl_xor(pv1, 16);
    pv1 += __shfl_xor(pv1, 32);
    if (l < 16) {
        v[(size_t)a * 128 + f0] = pv0;
        v[(size_t)a * 128 + f1] = pv1;
    }
}

// ---------------------------------------------------------------------------
// K3: two chained dense layers, swizzled coalesced weight loads.
// ---------------------------------------------------------------------------
__global__ __launch_bounds__(256, 4) void mgemm2_kernel(
    const float* A,
    const unsigned* __restrict__ W1h, const unsigned* __restrict__ W1l,
    const float* __restrict__ bias1, int nssp1,
    const unsigned* __restrict__ W2h, const unsigned* __restrict__ W2l,
    const float* __restrict__ bias2, int nssp2,
    float* C)
{
    extern __shared__ float smf[];
    __bf16* Ah = (__bf16*)smf;              // [16][136]
    __bf16* Al = (__bf16*)(smf + 1088);
    unsigned* AhU = (unsigned*)Ah;
    unsigned* AlU = (unsigned*)Al;

    const int t = threadIdx.x;
    const int atom0 = blockIdx.x * 16;
    const int w = t >> 6, l = t & 63, m = l & 15, q = l >> 4;

    {
        const float4* A4 = (const float4*)(A + (size_t)atom0 * 128);
        #pragma unroll
        for (int r = 0; r < 2; ++r) {
            int lin4 = r * 256 + t;
            int a = lin4 >> 5, k4 = lin4 & 31;
            float4 xv = A4[lin4];
            __bf16 h0=(__bf16)xv.x, h1=(__bf16)xv.y, h2=(__bf16)xv.z, h3=(__bf16)xv.w;
            int idx = a * 68 + 2 * k4;
            AhU[idx]     = pack2h(h0, h1);
            AhU[idx + 1] = pack2h(h2, h3);
            AlU[idx]     = pack2f(xv.x - (float)h0, xv.y - (float)h1);
            AlU[idx + 1] = pack2f(xv.z - (float)h2, xv.w - (float)h3);
        }
    }
    __syncthreads();

    bf16x8_t ah[4], al[4];
    #pragma unroll
    for (int kk = 0; kk < 4; ++kk) {
        int off = m * 136 + 32 * kk + 8 * q;
        ah[kk] = *(const bf16x8_t*)&Ah[off];
        al[kk] = *(const bf16x8_t*)&Al[off];
    }
    f32x4_t acc[2];
    int fidx[2];
    #pragma unroll
    for (int ft = 0; ft < 2; ++ft) {
        fidx[ft] = 16 * (2 * w + ft) + m;
        float b = bias1 ? bias1[fidx[ft]] : 0.0f;
        acc[ft] = (f32x4_t){b, b, b, b};
    }
    #pragma unroll
    for (int ft = 0; ft < 2; ++ft) {
        #pragma unroll
        for (int kk = 0; kk < 4; ++kk) {
            int wo = ((2 * w + ft) * 4 + kk) * 256 + l * 4;
            bf16x8_t wh = *(const bf16x8_t*)(W1h + wo);
            bf16x8_t wl = *(const bf16x8_t*)(W1l + wo);
            acc[ft] = __builtin_amdgcn_mfma_f32_16x16x32_bf16(ah[kk], wh, acc[ft], 0, 0, 0);
            acc[ft] = __builtin_amdgcn_mfma_f32_16x16x32_bf16(ah[kk], wl, acc[ft], 0, 0, 0);
            acc[ft] = __builtin_amdgcn_mfma_f32_16x16x32_bf16(al[kk], wh, acc[ft], 0, 0, 0);
        }
    }
    #pragma unroll
    for (int ft = 0; ft < 2; ++ft)
        #pragma unroll
        for (int r = 0; r < 4; ++r) {
            float o = acc[ft][r];
            if (nssp1 >= 1) o = sspf(o);
            if (nssp1 >= 2) o = sspf(o);
            acc[ft][r] = o;
        }

    __syncthreads();
    #pragma unroll
    for (int ft = 0; ft < 2; ++ft)
        #pragma unroll
        for (int r = 0; r < 4; ++r) {
            float o = acc[ft][r];
            __bf16 hh = (__bf16)o;
            Ah[(4 * q + r) * 136 + fidx[ft]] = hh;
            Al[(4 * q + r) * 136 + fidx[ft]] = (__bf16)(o - (float)hh);
        }
    __syncthreads();

    #pragma unroll
    for (int kk = 0; kk < 4; ++kk) {
        int off = m * 136 + 32 * kk + 8 * q;
        ah[kk] = *(const bf16x8_t*)&Ah[off];
        al[kk] = *(const bf16x8_t*)&Al[off];
    }
    #pragma unroll
    for (int ft = 0; ft < 2; ++ft) {
        float b = bias2 ? bias2[fidx[ft]] : 0.0f;
        acc[ft] = (f32x4_t){b, b, b, b};
    }
    #pragma unroll
    for (int ft = 0; ft < 2; ++ft) {
        #pragma unroll
        for (int kk = 0; kk < 4; ++kk) {
            int wo = ((2 * w + ft) * 4 + kk) * 256 + l * 4;
            bf16x8_t wh = *(const bf16x8_t*)(W2h + wo);
            bf16x8_t wl = *(const bf16x8_t*)(W2l + wo);
            acc[ft] = __builtin_amdgcn_mfma_f32_16x16x32_bf16(ah[kk], wh, acc[ft], 0, 0, 0);
            acc[ft] = __builtin_amdgcn_mfma_f32_16x16x32_bf16(ah[kk], wl, acc[ft], 0, 0, 0);
            acc[ft] = __builtin_amdgcn_mfma_f32_16x16x32_bf16(al[kk], wh, acc[ft], 0, 0, 0);
        }
    }
    #pragma unroll
    for (int ft = 0; ft < 2; ++ft)
        #pragma unroll
        for (int r = 0; r < 4; ++r) {
            float o = acc[ft][r];
            if (nssp2 >= 1) o = sspf(o);
            if (nssp2 >= 2) o = sspf(o);
            C[(size_t)(atom0 + 4 * q + r) * 128 + fidx[ft]] = o;
        }
}

// ---------------------------------------------------------------------------
extern "C" void kernel_launch(void* const* d_in, const int* in_sizes, int n_in,
                              void* d_out, int out_size, void* d_ws, size_t ws_size,
                              hipStream_t stream) {
    const float* x        = (const float*)d_in[0];
    const float* rij      = (const float*)d_in[1];
    const int*   nbrs     = (const int*)  d_in[2];
    const float* mask     = (const float*)d_in[3];
    const float* fij      = (const float*)d_in[4];
    const float* W_in2f   = (const float*)d_in[5];
    const float* W_f1     = (const float*)d_in[6];
    const float* b_f1     = (const float*)d_in[7];
    const float* W_f2     = (const float*)d_in[8];
    const float* b_f2     = (const float*)d_in[9];
    const float* W_f2out  = (const float*)d_in[10];
    const float* b_f2out  = (const float*)d_in[11];
    const float* W_dense  = (const float*)d_in[12];
    const float* b_dense  = (const float*)d_in[13];
    float* out = (float*)d_out;

    // ws: y [8192][128] f32 @0 (4 MB) | prep 240 KB @4 MB.
    float*    y    = (float*)d_ws;
    unsigned* prep = (unsigned*)((char*)d_ws + (4u << 20));
    const unsigned* W1S    = prep;
    const unsigned* W2S    = prep + 4096;
    const unsigned* f2o_h  = prep + 12288, *f2o_l  = prep + 20480;
    const unsigned* den_h  = prep + 28672, *den_l  = prep + 36864;
    const unsigned* in2f_h = prep + 45056, *in2f_l = prep + 53248;

    const int MG2_LDS = 2176 * 4;    // 8704 B

    // K0: all weight prep (61440 items)
    prep_kernel<<<240, 256, 0, stream>>>(W_f1, W_f2, W_f2out, W_dense, W_in2f, prep);
    // K1: y = x @ W_in2f^T  (preconverted weights, 1024 blocks)
    k1_kernel<<<1024, 256, 0, stream>>>(x, in2f_h, in2f_l, y);
    // K2: filter net + cutoff + gather + aggregate -> d_out (v)
    interaction_kernel<<<8192, 256, 0, stream>>>(
        rij, nbrs, mask, fij, b_f1, b_f2, W1S, W2S, y, out);
    // K3: out = ssp(ssp(v@W_f2out^T+b)) @ W_dense^T + b_dense, in-place
    mgemm2_kernel<<<512, 256, MG2_LDS, stream>>>(
        out, f2o_h, f2o_l, b_f2out, 2, den_h, den_l, b_dense, 0, out);
}

// Round 3
// 255.299 us; speedup vs baseline: 1.1122x; 1.1122x over previous
//
#include <hip/hip_runtime.h>
#include <math.h>

// SchNet interaction, MFMA bf16-split, swizzled-weight design, R3.
// Nb=8, Na=1024, Nnbh=64, A=F=128, S=50.
// prep u32 layout (fragment-linear swizzled order, 1 KB/wave coalesced):
//   W1S    @0      (4096):  [ftile][kh][l][4]   W_f1 bf16, K 50->64 pad
//   W2S    @4096   (8192):  [ftile][kq][l][4]   W_f2 bf16
//   F2O_h  @12288, F2O_l @20480   W_f2out hi/lo split, swizzled
//   DEN_h  @28672, DEN_l @36864   W_dense  hi/lo split
//   IN2F_h @45056, IN2F_l @53248  W_in2f   hi/lo split
// fragment addr for (ftile,kq): (ftile*4+kq)*256 + l*4 (u32), f = 16*ftile+m.
//
// R3 (post-mortem of R2's regression): vmcnt drains IN ORDER, so gather loads
// issued before fij blocked phase A. Now: W2 frags hoisted to kernel start;
// gather loads issued en-bloc right AFTER the barrier (no competing vmem in
// phase B), draining under the mt-loop's MFMA+LDS work.

#define RCUT  5.0f
#define LOG2F_ 0.69314718055994530942f
#define LOG2E_ 1.44269504088896340736f

typedef __bf16 bf16x8_t __attribute__((ext_vector_type(8)));
typedef float  f32x4_t  __attribute__((ext_vector_type(4)));

static __device__ __forceinline__ float sspf(float x) {
    // softplus(x) - ln2 = max(x,0) + ln2*log2(1 + 2^(-|x|*log2e)) - ln2
    float e  = exp2f(-LOG2E_ * fabsf(x));
    float lg = log2f(1.0f + e);
    return fmaf(lg, LOG2F_, fmaxf(x, 0.0f) - LOG2F_);
}
static __device__ __forceinline__ unsigned pack2h(__bf16 a, __bf16 b) {
    union { __bf16 h[2]; unsigned u; } un; un.h[0] = a; un.h[1] = b; return un.u;
}
static __device__ __forceinline__ unsigned pack2f(float a, float b) {
    return pack2h((__bf16)a, (__bf16)b);
}

// ---------------------------------------------------------------------------
// K0: weight prep (all swizzled conversions). 240 blocks x 256 = 61440 items.
// ---------------------------------------------------------------------------
__global__ __launch_bounds__(256) void prep_kernel(
    const float* __restrict__ W1, const float* __restrict__ W2,
    const float* __restrict__ Wb,   // W_f2out
    const float* __restrict__ Wc,   // W_dense
    const float* __restrict__ Wf,   // W_in2f
    unsigned* __restrict__ prep)
{
    int i = blockIdx.x * 256 + threadIdx.x;
    if (i < 4096) {                        // W1S (K pad 50->64)
        int sw = i >> 10, ft = (i >> 9) & 1, kh = (i >> 8) & 1;
        int sl = (i >> 2) & 63, j = i & 3;
        int sq = sl >> 4, sm = sl & 15;
        int f = 32 * sw + 16 * ft + sm;
        int c = kh * 16 + 4 * sq + j;
        int k0 = 2 * c, k1 = 2 * c + 1;
        float a = (k0 < 50) ? W1[f * 50 + k0] : 0.0f;
        float b = (k1 < 50) ? W1[f * 50 + k1] : 0.0f;
        prep[i] = pack2f(a, b);
    } else if (i < 12288) {                // W2S
        int s = i - 4096;
        int sw = s >> 11, ft = (s >> 10) & 1, kq = (s >> 8) & 3;
        int sl = (s >> 2) & 63, j = s & 3;
        int sq = sl >> 4, sm = sl & 15;
        int f = 32 * sw + 16 * ft + sm;
        int c = 16 * kq + 4 * sq + j;
        float2 wv = ((const float2*)W2)[f * 64 + c];
        prep[i] = pack2f(wv.x, wv.y);
    } else {                               // f2out / dense / in2f, hi+lo
        int s = i - 12288;
        int L = s >> 14;                   // 0: f2out, 1: dense, 2: in2f
        int r = s & 16383;
        int hl = r >> 13;                  // 0: hi, 1: lo
        int e = r & 8191;
        int sw = e >> 11, ft = (e >> 10) & 1, kq = (e >> 8) & 3;
        int sl = (e >> 2) & 63, j = e & 3;
        int sq = sl >> 4, sm = sl & 15;
        int f = 32 * sw + 16 * ft + sm;
        int c = 16 * kq + 4 * sq + j;
        const float* src = (L == 0) ? Wb : (L == 1) ? Wc : Wf;
        float2 wv = ((const float2*)src)[f * 64 + c];
        if (hl == 0) {
            prep[i] = pack2h((__bf16)wv.x, (__bf16)wv.y);
        } else {
            __bf16 h0 = (__bf16)wv.x, h1 = (__bf16)wv.y;
            prep[i] = pack2f(wv.x - (float)h0, wv.y - (float)h1);
        }
    }
}

// ---------------------------------------------------------------------------
// K1: y = x @ W_in2f^T using preconverted swizzled weights.
// 1024 blocks: (atom-tile of 16) x (f-half of 64). 4 blocks/CU.
// ---------------------------------------------------------------------------
__global__ __launch_bounds__(256, 4) void k1_kernel(
    const float* __restrict__ x,
    const unsigned* __restrict__ Wh, const unsigned* __restrict__ Wl,
    float* __restrict__ yout)
{
    __shared__ __bf16 Ah[16 * 136];
    __shared__ __bf16 Al[16 * 136];

    const int t = threadIdx.x;
    const int atom0 = (blockIdx.x >> 1) * 16;
    const int fh = blockIdx.x & 1;
    const int w = t >> 6, l = t & 63, m = l & 15, q = l >> 4;

    {
        const float4* A4 = (const float4*)(x + (size_t)atom0 * 128);
        unsigned* AhU = (unsigned*)Ah;
        unsigned* AlU = (unsigned*)Al;
        #pragma unroll
        for (int r = 0; r < 2; ++r) {
            int lin4 = r * 256 + t;
            int a = lin4 >> 5, k4 = lin4 & 31;
            float4 xv = A4[lin4];
            __bf16 h0=(__bf16)xv.x, h1=(__bf16)xv.y, h2=(__bf16)xv.z, h3=(__bf16)xv.w;
            int idx = a * 68 + 2 * k4;
            AhU[idx]     = pack2h(h0, h1);
            AhU[idx + 1] = pack2h(h2, h3);
            AlU[idx]     = pack2f(xv.x - (float)h0, xv.y - (float)h1);
            AlU[idx + 1] = pack2f(xv.z - (float)h2, xv.w - (float)h3);
        }
    }
    __syncthreads();

    const int ftile = fh * 4 + w;
    const int f = 16 * ftile + m;
    f32x4_t acc = {0.f, 0.f, 0.f, 0.f};
    #pragma unroll
    for (int kk = 0; kk < 4; ++kk) {
        int off = m * 136 + 32 * kk + 8 * q;
        bf16x8_t ah = *(const bf16x8_t*)&Ah[off];
        bf16x8_t al = *(const bf16x8_t*)&Al[off];
        int wo = (ftile * 4 + kk) * 256 + l * 4;
        bf16x8_t wh = *(const bf16x8_t*)(Wh + wo);
        bf16x8_t wl = *(const bf16x8_t*)(Wl + wo);
        acc = __builtin_amdgcn_mfma_f32_16x16x32_bf16(ah, wh, acc, 0, 0, 0);
        acc = __builtin_amdgcn_mfma_f32_16x16x32_bf16(ah, wl, acc, 0, 0, 0);
        acc = __builtin_amdgcn_mfma_f32_16x16x32_bf16(al, wh, acc, 0, 0, 0);
    }
    #pragma unroll
    for (int r = 0; r < 4; ++r)
        yout[(size_t)(atom0 + 4 * q + r) * 128 + f] = acc[r];
}

// ---------------------------------------------------------------------------
// K2 interaction. 1 atom/block, 256 thr = 4 waves, ONE barrier.
// W2 frags loaded at start; y gathers issued en-bloc after barrier, draining
// under the mt-loop's MFMA/LDS work.
// ---------------------------------------------------------------------------
__global__ __launch_bounds__(256, 4) void interaction_kernel(
    const float* __restrict__ rij, const int* __restrict__ nbrs,
    const float* __restrict__ mask, const float* __restrict__ fij,
    const float* __restrict__ b1, const float* __restrict__ b2,
    const unsigned* __restrict__ W1S,   // swizzled [8][2][64][4] u32
    const unsigned* __restrict__ W2S,   // swizzled [8][4][64][4] u32
    const float* __restrict__ y, float* __restrict__ v)
{
    __shared__ __bf16 Hh[64 * 136];
    __shared__ __bf16 Hl[64 * 136];
    __shared__ float  cb[64];
    __shared__ int    nb[64];

    const int t  = threadIdx.x;
    const int a  = blockIdx.x;
    const int bi = a >> 10;
    const int p0 = a * 64;
    const int w = t >> 6, l = t & 63, m = l & 15, q = l >> 4;
    const int f0 = 32 * w + m;
    const int f1 = f0 + 16;

    // W2 fragments: static addresses, L2-resident -> complete under phase A.
    bf16x8_t w2f0[4], w2f1[4];
    #pragma unroll
    for (int kq = 0; kq < 4; ++kq) {
        w2f0[kq] = *(const bf16x8_t*)(W2S + ((w * 2 + 0) * 4 + kq) * 256 + l * 4);
        w2f1[kq] = *(const bf16x8_t*)(W2S + ((w * 2 + 1) * 4 + kq) * 256 + l * 4);
    }

    if (t < 64) {
        float r = rij[p0 + t];
        cb[t] = (r <= RCUT) ? mask[p0 + t] : 0.0f;
        nb[t] = (bi << 10) + nbrs[p0 + t];
    }

    // ---- phase A: H[n][f] = ssp(fij @ W1^T + b1), wave owns 16 rows ----
    {
        const float* frow = fij + (size_t)(p0 + 16 * w + m) * 50;
        float kv[16];
        #pragma unroll
        for (int j2 = 0; j2 < 4; ++j2) {
            float2 xv = *(const float2*)(frow + 8 * q + 2 * j2);
            kv[2 * j2] = xv.x; kv[2 * j2 + 1] = xv.y;
        }
        #pragma unroll
        for (int j2 = 0; j2 < 4; ++j2) {
            int k = 32 + 8 * q + 2 * j2;
            float2 xv = make_float2(0.f, 0.f);
            if (k < 50) xv = *(const float2*)(frow + k);
            kv[8 + 2 * j2] = xv.x; kv[9 + 2 * j2] = xv.y;
        }
        union { __bf16 h[16]; bf16x8_t v8[2]; } uh, ul;
        #pragma unroll
        for (int k = 0; k < 16; ++k) {
            __bf16 hi = (__bf16)kv[k];
            uh.h[k] = hi;
            ul.h[k] = (__bf16)(kv[k] - (float)hi);
        }
        #pragma unroll 2
        for (int ftile = 0; ftile < 8; ++ftile) {
            float bb = b1[16 * ftile + m];
            f32x4_t acch = {bb, bb, bb, bb};
            f32x4_t accl = {0.f, 0.f, 0.f, 0.f};
            bf16x8_t w0 = *(const bf16x8_t*)(W1S + (ftile * 2 + 0) * 256 + l * 4);
            bf16x8_t w1 = *(const bf16x8_t*)(W1S + (ftile * 2 + 1) * 256 + l * 4);
            acch = __builtin_amdgcn_mfma_f32_16x16x32_bf16(uh.v8[0], w0, acch, 0, 0, 0);
            accl = __builtin_amdgcn_mfma_f32_16x16x32_bf16(ul.v8[0], w0, accl, 0, 0, 0);
            acch = __builtin_amdgcn_mfma_f32_16x16x32_bf16(uh.v8[1], w1, acch, 0, 0, 0);
            accl = __builtin_amdgcn_mfma_f32_16x16x32_bf16(ul.v8[1], w1, accl, 0, 0, 0);
            #pragma unroll
            for (int r = 0; r < 4; ++r) {
                int n = 16 * w + 4 * q + r;
                float hv = sspf(acch[r] + accl[r]);
                __bf16 hh = (__bf16)hv;
                Hh[n * 136 + 16 * ftile + m] = hh;
                Hl[n * 136 + 16 * ftile + m] = (__bf16)(hv - (float)hh);
            }
        }
    }
    __syncthreads();   // the ONLY barrier

    // ---- phase B: issue all 32 y gathers, then MFMAs hide the drain ----
    float yv0[16], yv1[16];
    #pragma unroll
    for (int i = 0; i < 16; ++i) {
        int n = 16 * (i >> 2) + 4 * q + (i & 3);
        const float* yrow = y + (size_t)nb[n] * 128;
        yv0[i] = yrow[f0];
        yv1[i] = yrow[f1];
    }

    const float bb2_0 = b2[f0], bb2_1 = b2[f1];
    float pv0 = 0.0f, pv1 = 0.0f;
    #pragma unroll
    for (int mt = 0; mt < 4; ++mt) {
        f32x4_t a0h = {bb2_0, bb2_0, bb2_0, bb2_0};
        f32x4_t a0l = {0.f, 0.f, 0.f, 0.f};
        f32x4_t a1h = {bb2_1, bb2_1, bb2_1, bb2_1};
        f32x4_t a1l = {0.f, 0.f, 0.f, 0.f};
        #pragma unroll
        for (int kq = 0; kq < 4; ++kq) {
            int hoff = (16 * mt + m) * 136 + 32 * kq + 8 * q;
            bf16x8_t hh = *(const bf16x8_t*)&Hh[hoff];
            bf16x8_t hl = *(const bf16x8_t*)&Hl[hoff];
            a0h = __builtin_amdgcn_mfma_f32_16x16x32_bf16(hh, w2f0[kq], a0h, 0, 0, 0);
            a0l = __builtin_amdgcn_mfma_f32_16x16x32_bf16(hl, w2f0[kq], a0l, 0, 0, 0);
            a1h = __builtin_amdgcn_mfma_f32_16x16x32_bf16(hh, w2f1[kq], a1h, 0, 0, 0);
            a1l = __builtin_amdgcn_mfma_f32_16x16x32_bf16(hl, w2f1[kq], a1l, 0, 0, 0);
        }
        #pragma unroll
        for (int r = 0; r < 4; ++r) {
            int n = 16 * mt + 4 * q + r;
            float cn = cb[n];
            float s0 = a0h[r] + a0l[r];
            float s1 = a1h[r] + a1l[r];
            pv0 = fmaf(cn * yv0[mt * 4 + r], s0, pv0);
            pv1 = fmaf(cn * yv1[mt * 4 + r], s1, pv1);
        }
    }
    pv0 += __shfl_xor(pv0, 16);
    pv0 += __shfl_xor(pv0, 32);
    pv1 += __shfl_xor(pv1, 16);
    pv1 += __shfl_xor(pv1, 32);
    if (l < 16) {
        v[(size_t)a * 128 + f0] = pv0;
        v[(size_t)a * 128 + f1] = pv1;
    }
}

// ---------------------------------------------------------------------------
// K3: two chained dense layers, swizzled coalesced weight loads.
// ---------------------------------------------------------------------------
__global__ __launch_bounds__(256, 4) void mgemm2_kernel(
    const float* A,
    const unsigned* __restrict__ W1h, const unsigned* __restrict__ W1l,
    const float* __restrict__ bias1, int nssp1,
    const unsigned* __restrict__ W2h, const unsigned* __restrict__ W2l,
    const float* __restrict__ bias2, int nssp2,
    float* C)
{
    extern __shared__ float smf[];
    __bf16* Ah = (__bf16*)smf;              // [16][136]
    __bf16* Al = (__bf16*)(smf + 1088);
    unsigned* AhU = (unsigned*)Ah;
    unsigned* AlU = (unsigned*)Al;

    const int t = threadIdx.x;
    const int atom0 = blockIdx.x * 16;
    const int w = t >> 6, l = t & 63, m = l & 15, q = l >> 4;

    {
        const float4* A4 = (const float4*)(A + (size_t)atom0 * 128);
        #pragma unroll
        for (int r = 0; r < 2; ++r) {
            int lin4 = r * 256 + t;
            int a = lin4 >> 5, k4 = lin4 & 31;
            float4 xv = A4[lin4];
            __bf16 h0=(__bf16)xv.x, h1=(__bf16)xv.y, h2=(__bf16)xv.z, h3=(__bf16)xv.w;
            int idx = a * 68 + 2 * k4;
            AhU[idx]     = pack2h(h0, h1);
            AhU[idx + 1] = pack2h(h2, h3);
            AlU[idx]     = pack2f(xv.x - (float)h0, xv.y - (float)h1);
            AlU[idx + 1] = pack2f(xv.z - (float)h2, xv.w - (float)h3);
        }
    }
    __syncthreads();

    bf16x8_t ah[4], al[4];
    #pragma unroll
    for (int kk = 0; kk < 4; ++kk) {
        int off = m * 136 + 32 * kk + 8 * q;
        ah[kk] = *(const bf16x8_t*)&Ah[off];
        al[kk] = *(const bf16x8_t*)&Al[off];
    }
    f32x4_t acc[2];
    int fidx[2];
    #pragma unroll
    for (int ft = 0; ft < 2; ++ft) {
        fidx[ft] = 16 * (2 * w + ft) + m;
        float b = bias1 ? bias1[fidx[ft]] : 0.0f;
        acc[ft] = (f32x4_t){b, b, b, b};
    }
    #pragma unroll
    for (int ft = 0; ft < 2; ++ft) {
        #pragma unroll
        for (int kk = 0; kk < 4; ++kk) {
            int wo = ((2 * w + ft) * 4 + kk) * 256 + l * 4;
            bf16x8_t wh = *(const bf16x8_t*)(W1h + wo);
            bf16x8_t wl = *(const bf16x8_t*)(W1l + wo);
            acc[ft] = __builtin_amdgcn_mfma_f32_16x16x32_bf16(ah[kk], wh, acc[ft], 0, 0, 0);
            acc[ft] = __builtin_amdgcn_mfma_f32_16x16x32_bf16(ah[kk], wl, acc[ft], 0, 0, 0);
            acc[ft] = __builtin_amdgcn_mfma_f32_16x16x32_bf16(al[kk], wh, acc[ft], 0, 0, 0);
        }
    }
    #pragma unroll
    for (int ft = 0; ft < 2; ++ft)
        #pragma unroll
        for (int r = 0; r < 4; ++r) {
            float o = acc[ft][r];
            if (nssp1 >= 1) o = sspf(o);
            if (nssp1 >= 2) o = sspf(o);
            acc[ft][r] = o;
        }

    __syncthreads();
    #pragma unroll
    for (int ft = 0; ft < 2; ++ft)
        #pragma unroll
        for (int r = 0; r < 4; ++r) {
            float o = acc[ft][r];
            __bf16 hh = (__bf16)o;
            Ah[(4 * q + r) * 136 + fidx[ft]] = hh;
            Al[(4 * q + r) * 136 + fidx[ft]] = (__bf16)(o - (float)hh);
        }
    __syncthreads();

    #pragma unroll
    for (int kk = 0; kk < 4; ++kk) {
        int off = m * 136 + 32 * kk + 8 * q;
        ah[kk] = *(const bf16x8_t*)&Ah[off];
        al[kk] = *(const bf16x8_t*)&Al[off];
    }
    #pragma unroll
    for (int ft = 0; ft < 2; ++ft) {
        float b = bias2 ? bias2[fidx[ft]] : 0.0f;
        acc[ft] = (f32x4_t){b, b, b, b};
    }
    #pragma unroll
    for (int ft = 0; ft < 2; ++ft) {
        #pragma unroll
        for (int kk = 0; kk < 4; ++kk) {
            int wo = ((2 * w + ft) * 4 + kk) * 256 + l * 4;
            bf16x8_t wh = *(const bf16x8_t*)(W2h + wo);
            bf16x8_t wl = *(const bf16x8_t*)(W2l + wo);
            acc[ft] = __builtin_amdgcn_mfma_f32_16x16x32_bf16(ah[kk], wh, acc[ft], 0, 0, 0);
            acc[ft] = __builtin_amdgcn_mfma_f32_16x16x32_bf16(ah[kk], wl, acc[ft], 0, 0, 0);
            acc[ft] = __builtin_amdgcn_mfma_f32_16x16x32_bf16(al[kk], wh, acc[ft], 0, 0, 0);
        }
    }
    #pragma unroll
    for (int ft = 0; ft < 2; ++ft)
        #pragma unroll
        for (int r = 0; r < 4; ++r) {
            float o = acc[ft][r];
            if (nssp2 >= 1) o = sspf(o);
            if (nssp2 >= 2) o = sspf(o);
            C[(size_t)(atom0 + 4 * q + r) * 128 + fidx[ft]] = o;
        }
}

// ---------------------------------------------------------------------------
extern "C" void kernel_launch(void* const* d_in, const int* in_sizes, int n_in,
                              void* d_out, int out_size, void* d_ws, size_t ws_size,
                              hipStream_t stream) {
    const float* x        = (const float*)d_in[0];
    const float* rij      = (const float*)d_in[1];
    const int*   nbrs     = (const int*)  d_in[2];
    const float* mask     = (const float*)d_in[3];
    const float* fij      = (const float*)d_in[4];
    const float* W_in2f   = (const float*)d_in[5];
    const float* W_f1     = (const float*)d_in[6];
    const float* b_f1     = (const float*)d_in[7];
    const float* W_f2     = (const float*)d_in[8];
    const float* b_f2     = (const float*)d_in[9];
    const float* W_f2out  = (const float*)d_in[10];
    const float* b_f2out  = (const float*)d_in[11];
    const float* W_dense  = (const float*)d_in[12];
    const float* b_dense  = (const float*)d_in[13];
    float* out = (float*)d_out;

    // ws: y [8192][128] f32 @0 (4 MB) | prep 240 KB @4 MB.
    float*    y    = (float*)d_ws;
    unsigned* prep = (unsigned*)((char*)d_ws + (4u << 20));
    const unsigned* W1S    = prep;
    const unsigned* W2S    = prep + 4096;
    const unsigned* f2o_h  = prep + 12288, *f2o_l  = prep + 20480;
    const unsigned* den_h  = prep + 28672, *den_l  = prep + 36864;
    const unsigned* in2f_h = prep + 45056, *in2f_l = prep + 53248;

    const int MG2_LDS = 2176 * 4;    // 8704 B

    // K0: all weight prep (61440 items)
    prep_kernel<<<240, 256, 0, stream>>>(W_f1, W_f2, W_f2out, W_dense, W_in2f, prep);
    // K1: y = x @ W_in2f^T  (preconverted weights, 1024 blocks)
    k1_kernel<<<1024, 256, 0, stream>>>(x, in2f_h, in2f_l, y);
    // K2: filter net + cutoff + gather + aggregate -> d_out (v)
    interaction_kernel<<<8192, 256, 0, stream>>>(
        rij, nbrs, mask, fij, b_f1, b_f2, W1S, W2S, y, out);
    // K3: out = ssp(ssp(v@W_f2out^T+b)) @ W_dense^T + b_dense, in-place
    mgemm2_kernel<<<512, 256, MG2_LDS, stream>>>(
        out, f2o_h, f2o_l, b_f2out, 2, den_h, den_l, b_dense, 0, out);
}